// Round 3
// baseline (176.125 us; speedup 1.0000x reference)
//
#include <hip/hip_runtime.h>
#include <math.h>

// Problem constants (fixed by setup_inputs)
#define B_  4
#define C_  256
#define W_  64
#define M_  4096          // ref locations (H*W)
#define N_  4096          // anchors per batch (== M_)
#define THRESH_ 0.4f      // relu(0.6 - dist) = relu(sim - 0.4)

typedef __attribute__((ext_vector_type(8))) short bf16x8;
typedef __attribute__((ext_vector_type(4))) float f32x4;

__device__ __forceinline__ short f2bf(float x) {       // RNE float->bf16
    union { float f; unsigned u; } v; v.f = x;
    unsigned r = v.u + 0x7fffu + ((v.u >> 16) & 1u);
    return (short)(r >> 16);
}
__device__ __forceinline__ float bf2f(short s) {
    union { unsigned u; float f; } v;
    v.u = ((unsigned)(unsigned short)s) << 16;
    return v.f;
}
__device__ __forceinline__ void gload_lds16(const void* g, void* l) {
    __builtin_amdgcn_global_load_lds(
        (const __attribute__((address_space(1))) void*)g,
        (__attribute__((address_space(3))) void*)l, 16, 0, 0);
}

// ---------------------------------------------------------------------------
// Workspace layout (bytes):
//   anchors (bf16) : B*N*C*2 = 8,388,608     [b][n][c]
//   refT    (bf16) : B*M*C*2 = 8,388,608     [b][m][c]  (transposed ref)
//   ia (1/a_norm)  : B*N*4   =    65,536
//   ir (1/r_norm)  : B*M*4   =    65,536
//   diag           : B*N*4   =    65,536     1 - sim at positive location
//   ssum           : 4*B*M*4 =   262,144     partial sums for r_norm
//   rowsum         : B*N*4   =    65,536     sum of relu(sim-0.4) per row
//   rowcnt         : B*N*4   =    65,536
//   flagcnt        : 256
//   flaglist       : B*N*4   =    65,536
// ---------------------------------------------------------------------------
#define OFF_ANCH   0
#define OFF_REFT   8388608
#define OFF_IA     16777216
#define OFF_IR     16842752
#define OFF_DIAG   16908288
#define OFF_SSUM   16973824
#define OFF_ROWSUM 17235968
#define OFF_ROWCNT 17301504
#define OFF_FLAGC  17367040
#define OFF_FLAGL  17367296

// --------------------------- gather + inv anchor norms ---------------------
// one block per (b,n); thread c loads sketch[b, c, a_idx] (column gather)
__global__ __launch_bounds__(256) void gather_kernel(
    const float* __restrict__ sketch,
    const int* __restrict__ ay, const int* __restrict__ ax,
    short* __restrict__ anchors, float* __restrict__ ia)
{
    const int pair = blockIdx.x;            // b*N + n
    const int b = pair >> 12;
    const int c = threadIdx.x;
    const int idx = ay[pair] * W_ + ax[pair];
    const float v = sketch[((size_t)(b * C_ + c)) * M_ + idx];
    anchors[(size_t)pair * C_ + c] = f2bf(v);

    __shared__ float red[256];
    red[c] = v * v;
    __syncthreads();
    for (int s = 128; s > 0; s >>= 1) {
        if (c < s) red[c] += red[c + s];
        __syncthreads();
    }
    if (c == 0) ia[pair] = rsqrtf(red[0]);
}

// ------------------- ref convert+transpose + r_norm partials ---------------
// thread owns (b, m, c-quarter): reads ref[b][c][m] coalesced across threads,
// writes refT[b][m][cq*64..] contiguous per thread, fp32 sumsq partial.
__global__ __launch_bounds__(256) void convert_kernel(
    const float* __restrict__ ref, short* __restrict__ refT,
    float* __restrict__ ssum)
{
    const int bx = blockIdx.x;              // b*16 + mchunk
    const int cq = blockIdx.y;              // 0..3
    const int b  = bx >> 4;
    const int m  = (bx & 15) * 256 + threadIdx.x;

    const float* src = ref + ((size_t)(b * C_ + cq * 64)) * M_ + m;
    short* dst = refT + ((size_t)(b * M_ + m)) * C_ + cq * 64;

    float ss = 0.f;
#pragma unroll
    for (int j8 = 0; j8 < 8; ++j8) {
        bf16x8 v;
#pragma unroll
        for (int e = 0; e < 8; ++e) {
            float x = src[(size_t)(j8 * 8 + e) * M_];
            ss += x * x;
            v[e] = f2bf(x);
        }
        *reinterpret_cast<bf16x8*>(dst + j8 * 8) = v;
    }
    ssum[(size_t)cq * (B_ * M_) + b * M_ + m] = ss;
}

__global__ __launch_bounds__(256) void rnorm_fin_kernel(
    const float* __restrict__ ssum, float* __restrict__ ir)
{
    const int i = blockIdx.x * 256 + threadIdx.x;   // b*M + m
    float s = ssum[i] + ssum[B_ * M_ + i] + ssum[2 * B_ * M_ + i]
            + ssum[3 * B_ * M_ + i];
    ir[i] = rsqrtf(s);
}

// ------------------------------ MFMA GEMM + fused epilogue -----------------
// 128x128 output tile (m x n), BK=64, 256 threads = 4 waves (2x2 of 64x64).
// A-operand <- refT rows (m), B-operand <- anchors rows (n); both LDS tiles
// are [row][k] row-major so fragment reads are contiguous ds_read_b128.
// D[row=m_local][col=n_local]; C/D map: col=lane&15, row=(lane>>4)*4+reg.
#define BK 64

__global__ __launch_bounds__(256) void gemm_kernel(
    const short* __restrict__ anchors, const short* __restrict__ refT,
    const float* __restrict__ ia, const float* __restrict__ ir,
    float* __restrict__ diag, float* __restrict__ rowsum,
    int* __restrict__ rowcnt)
{
    const int mBase = blockIdx.x * 128;
    const int nBase = blockIdx.y * 128;
    const int b = blockIdx.z;
    const int tid = threadIdx.x;
    const int lane = tid & 63, wv = tid >> 6;
    const int wm = (wv >> 1) * 64, wn = (wv & 1) * 64;
    const int l15 = lane & 15, l4 = lane >> 4;

    __shared__ __align__(16) short Rs[128 * BK];   // refT tile  [m][k]
    __shared__ __align__(16) short As[128 * BK];   // anchor tile [n][k]

    const short* refT_b = refT + ((size_t)b * M_ + mBase) * C_;
    const short* anch_b = anchors + ((size_t)b * N_ + nBase) * C_;

    f32x4 acc[4][4] = {};   // [m-frag][n-frag]

    for (int k0 = 0; k0 < C_; k0 += BK) {
        // stage both 128xBK bf16 tiles: 16 x 1KB wave-chunks each
#pragma unroll
        for (int c = 0; c < 4; ++c) {
            const int cb = wv * 4 + c;               // 0..15
            const int row = cb * 8 + (lane >> 3);    // 0..127
            const int kk = (lane & 7) * 8;           // 0..56
            gload_lds16(refT_b + (size_t)row * C_ + k0 + kk, (char*)Rs + cb * 1024);
            gload_lds16(anch_b + (size_t)row * C_ + k0 + kk, (char*)As + cb * 1024);
        }
        __syncthreads();   // drains vmcnt before barrier

#pragma unroll
        for (int ks = 0; ks < 2; ++ks) {
            bf16x8 pm[4], pn[4];
#pragma unroll
            for (int f = 0; f < 4; ++f) {
                pm[f] = *reinterpret_cast<const bf16x8*>(
                    &Rs[(wm + f * 16 + l15) * BK + ks * 32 + l4 * 8]);
                pn[f] = *reinterpret_cast<const bf16x8*>(
                    &As[(wn + f * 16 + l15) * BK + ks * 32 + l4 * 8]);
            }
#pragma unroll
            for (int fi = 0; fi < 4; ++fi)
#pragma unroll
                for (int fj = 0; fj < 4; ++fj)
                    acc[fi][fj] = __builtin_amdgcn_mfma_f32_16x16x32_bf16(
                        pm[fi], pn[fj], acc[fi][fj], 0, 0, 0);
        }
        __syncthreads();
    }

    // epilogue: sim = dot * ia[n] * ir[m]; diag store + relu-threshold mining
    float irv[4][4];
#pragma unroll
    for (int fi = 0; fi < 4; ++fi)
#pragma unroll
        for (int r = 0; r < 4; ++r)
            irv[fi][r] = ir[b * M_ + mBase + wm + fi * 16 + l4 * 4 + r];

#pragma unroll
    for (int fj = 0; fj < 4; ++fj) {
        const int gn = nBase + wn + fj * 16 + l15;
        const float ian = ia[b * N_ + gn];
        float s = 0.f; int cnt = 0;
#pragma unroll
        for (int fi = 0; fi < 4; ++fi) {
#pragma unroll
            for (int r = 0; r < 4; ++r) {
                const int gm = mBase + wm + fi * 16 + l4 * 4 + r;
                const float sim = acc[fi][fj][r] * irv[fi][r] * ian;
                if (gm == gn) {
                    diag[b * N_ + gn] = 1.0f - sim;       // unique producer
                } else if (sim > THRESH_) {
                    s += sim - THRESH_; ++cnt;            // ~never fires
                }
            }
        }
        if (cnt) {
            atomicAdd(&rowsum[b * N_ + gn], s);
            atomicAdd(&rowcnt[b * N_ + gn], cnt);
        }
    }
}

// ------------------------- flag rows needing exact top-4 -------------------
__global__ __launch_bounds__(256) void flag_kernel(
    const int* __restrict__ rowcnt, int* __restrict__ flagcnt,
    int* __restrict__ flaglist)
{
    int i = blockIdx.x * 256 + threadIdx.x;   // b*N + n
    if (rowcnt[i] > 4) {
        int p = atomicAdd(flagcnt, 1);
        flaglist[p] = i;
    }
}

// -------- exact top-4 recompute for flagged rows (empty for this input) ----
__global__ __launch_bounds__(256) void fallback_kernel(
    const short* __restrict__ anchors, const short* __restrict__ refT,
    const float* __restrict__ ia, const float* __restrict__ ir,
    const int* __restrict__ flagcnt, const int* __restrict__ flaglist,
    float* __restrict__ rowsum)
{
    const int nflag = *flagcnt;
    __shared__ float av[C_];
    __shared__ float tops[256][4];
    for (int fi = blockIdx.x; fi < nflag; fi += gridDim.x) {
        const int row = flaglist[fi];
        const int b = row >> 12, n = row & (N_ - 1);
        __syncthreads();
        av[threadIdx.x] = bf2f(anchors[(size_t)row * C_ + threadIdx.x]);
        __syncthreads();
        const float ian = ia[row];
        float t0 = 0, t1 = 0, t2 = 0, t3 = 0;   // descending top-4 relu vals
        for (int m = threadIdx.x; m < M_; m += 256) {
            if (m == n) continue;
            const short* rp = refT + ((size_t)b * M_ + m) * C_;
            float dot = 0.f;
#pragma unroll 8
            for (int c = 0; c < C_; ++c) dot += av[c] * bf2f(rp[c]);
            float rl = dot * ian * ir[b * M_ + m] - THRESH_;
            if (rl > t3) {
                t3 = rl;
                if (t3 > t2) { float t = t2; t2 = t3; t3 = t; }
                if (t2 > t1) { float t = t1; t1 = t2; t2 = t; }
                if (t1 > t0) { float t = t0; t0 = t1; t1 = t; }
            }
        }
        tops[threadIdx.x][0] = t0; tops[threadIdx.x][1] = t1;
        tops[threadIdx.x][2] = t2; tops[threadIdx.x][3] = t3;
        __syncthreads();
        if (threadIdx.x == 0) {
            float s0 = 0, s1 = 0, s2 = 0, s3 = 0;
            for (int t = 0; t < 1024; ++t) {
                float v = tops[t >> 2][t & 3];
                if (v > s3) {
                    s3 = v;
                    if (s3 > s2) { float tt = s2; s2 = s3; s3 = tt; }
                    if (s2 > s1) { float tt = s1; s1 = s2; s2 = tt; }
                    if (s1 > s0) { float tt = s0; s0 = s1; s1 = tt; }
                }
            }
            rowsum[row] = s0 + s1 + s2 + s3;   // exact top-4 sum overrides
        }
        __syncthreads();
    }
}

// ------------------------------ final reduce -------------------------------
__global__ __launch_bounds__(256) void final_kernel(
    const float* __restrict__ rowsum, const float* __restrict__ diag,
    float* __restrict__ out)
{
    float sn = 0.f, sp = 0.f;
    for (int i = threadIdx.x; i < B_ * N_; i += 256) {
        sn += rowsum[i];
        sp += diag[i];
    }
    __shared__ float red[256];
    red[threadIdx.x] = sp * (1.0f / (B_ * N_)) + sn * (1.0f / (B_ * N_ * 4));
    __syncthreads();
    for (int s = 128; s > 0; s >>= 1) {
        if (threadIdx.x < s) red[threadIdx.x] += red[threadIdx.x + s];
        __syncthreads();
    }
    if (threadIdx.x == 0) out[0] = red[0];
}

// ---------------------------------------------------------------------------
extern "C" void kernel_launch(void* const* d_in, const int* in_sizes, int n_in,
                              void* d_out, int out_size, void* d_ws, size_t ws_size,
                              hipStream_t stream)
{
    const float* sketch = (const float*)d_in[0];
    const float* ref    = (const float*)d_in[1];
    const int*   ay     = (const int*)d_in[2];
    const int*   ax     = (const int*)d_in[3];
    float* out = (float*)d_out;

    char* ws = (char*)d_ws;
    short* anchors  = (short*)(ws + OFF_ANCH);
    short* refT     = (short*)(ws + OFF_REFT);
    float* ia       = (float*)(ws + OFF_IA);
    float* ir       = (float*)(ws + OFF_IR);
    float* diag     = (float*)(ws + OFF_DIAG);
    float* ssum     = (float*)(ws + OFF_SSUM);
    float* rowsum   = (float*)(ws + OFF_ROWSUM);
    int*   rowcnt   = (int*)(ws + OFF_ROWCNT);
    int*   flagcnt  = (int*)(ws + OFF_FLAGC);
    int*   flaglist = (int*)(ws + OFF_FLAGL);

    // zero rowsum, rowcnt, flagcnt in one contiguous memset
    hipMemsetAsync(ws + OFF_ROWSUM, 0, OFF_FLAGL - OFF_ROWSUM, stream);

    gather_kernel<<<B_ * N_, 256, 0, stream>>>(sketch, ay, ax, anchors, ia);
    convert_kernel<<<dim3(64, 4), 256, 0, stream>>>(ref, refT, ssum);
    rnorm_fin_kernel<<<(B_ * M_) / 256, 256, 0, stream>>>(ssum, ir);

    gemm_kernel<<<dim3(M_ / 128, N_ / 128, B_), 256, 0, stream>>>(
        anchors, refT, ia, ir, diag, rowsum, rowcnt);

    flag_kernel<<<(B_ * N_) / 256, 256, 0, stream>>>(rowcnt, flagcnt, flaglist);
    fallback_kernel<<<64, 256, 0, stream>>>(anchors, refT, ia, ir,
                                            flagcnt, flaglist, rowsum);
    final_kernel<<<1, 256, 0, stream>>>(rowsum, diag, out);
}

// Round 5
// 156.344 us; speedup vs baseline: 1.1265x; 1.1265x over previous
//
#include <hip/hip_runtime.h>
#include <math.h>

// Problem constants (fixed by setup_inputs)
#define B_  4
#define C_  256
#define W_  64
#define M_  4096          // ref locations (H*W)
#define N_  4096          // anchors per batch (== M_)
#define THRESH_ 0.4f      // relu(0.6 - dist) = relu(sim - 0.4)

typedef __attribute__((ext_vector_type(8))) short bf16x8;
typedef __attribute__((ext_vector_type(4))) float f32x4;

__device__ __forceinline__ short f2bf(float x) {       // RNE float->bf16
    union { float f; unsigned u; } v; v.f = x;
    unsigned r = v.u + 0x7fffu + ((v.u >> 16) & 1u);
    return (short)(r >> 16);
}
__device__ __forceinline__ float bf2f(short s) {
    union { unsigned u; float f; } v;
    v.u = ((unsigned)(unsigned short)s) << 16;
    return v.f;
}
__device__ __forceinline__ void gload_lds16(const void* g, void* l) {
    __builtin_amdgcn_global_load_lds(
        (const __attribute__((address_space(1))) void*)g,
        (__attribute__((address_space(3))) void*)l, 16, 0, 0);
}

// ---------------------------------------------------------------------------
// Workspace layout (bytes). ssum region (prep-only) is recycled after the
// norm-finalize for all post-prep scalars; stream order serializes access.
//   sketchT (bf16) : B*M*C*2 = 8,388,608   [b][m][c]
//   refT    (bf16) : B*M*C*2 = 8,388,608   [b][m][c]
//   isn (1/||s||)  : B*M*4   =    65,536   per sketch column
//   ir  (1/||r||)  : B*M*4   =    65,536   per ref column
//   ssum           : 8*B*M*4 =   524,288   [tensor*4+cq][b*M+m] partials
//     recycled: diag, rowsum, rowcnt, flagcnt, flaglist, aidx
// total = 17,432,576 <= proven ws bound (17,432,832)
// ---------------------------------------------------------------------------
#define OFF_SKT    0
#define OFF_REFT   8388608
#define OFF_ISN    16777216
#define OFF_IR     16842752
#define OFF_SSUM   16908288
#define OFF_DIAG   16908288            // recycled
#define OFF_ROWSUM 16973824
#define OFF_ROWCNT 17039360
#define OFF_FLAGC  17104896
#define OFF_FLAGL  17105152
#define OFF_AIDX   17170688            // ends 17236224 < 16908288+524288

// ------------- convert+transpose both tensors + column sumsq partials ------
// blockIdx: x = b*16 + mchunk, y = cq (64-elem c-quarter), z = tensor (0=sketch)
__global__ __launch_bounds__(256) void convert_kernel(
    const float* __restrict__ sketch, const float* __restrict__ ref,
    short* __restrict__ sketchT, short* __restrict__ refT,
    float* __restrict__ ssum)
{
    const int b  = blockIdx.x >> 4;
    const int m  = (blockIdx.x & 15) * 256 + threadIdx.x;
    const int cq = blockIdx.y;
    const int z  = blockIdx.z;

    const float* src = (z ? ref : sketch) + ((size_t)(b * C_ + cq * 64)) * M_ + m;
    short* dst = (z ? refT : sketchT) + ((size_t)(b * M_ + m)) * C_ + cq * 64;

    float ss = 0.f;
#pragma unroll
    for (int j8 = 0; j8 < 8; ++j8) {
        bf16x8 v;
#pragma unroll
        for (int e = 0; e < 8; ++e) {
            float x = src[(size_t)(j8 * 8 + e) * M_];
            ss += x * x;
            v[e] = f2bf(x);
        }
        *reinterpret_cast<bf16x8*>(dst + j8 * 8) = v;
    }
    ssum[(size_t)(z * 4 + cq) * (B_ * M_) + b * M_ + m] = ss;
}

__global__ __launch_bounds__(256) void fin_kernel(
    const float* __restrict__ ssum, float* __restrict__ isn,
    float* __restrict__ ir)
{
    const int i = blockIdx.x * 256 + threadIdx.x;   // b*M + m
    float s0 = 0.f, s1 = 0.f;
#pragma unroll
    for (int cq = 0; cq < 4; ++cq) {
        s0 += ssum[(size_t)cq * (B_ * M_) + i];
        s1 += ssum[(size_t)(4 + cq) * (B_ * M_) + i];
    }
    isn[i] = rsqrtf(s0);
    ir[i]  = rsqrtf(s1);
}

// ---------- anchor flat index + zero-init of GEMM accumulator arrays -------
__global__ __launch_bounds__(256) void prep2_kernel(
    const int* __restrict__ ay, const int* __restrict__ ax,
    int* __restrict__ aidx, float* __restrict__ rowsum,
    int* __restrict__ rowcnt, int* __restrict__ flagcnt)
{
    const int i = blockIdx.x * 256 + threadIdx.x;   // b*N + n
    aidx[i] = ay[i] * W_ + ax[i];
    rowsum[i] = 0.f;
    rowcnt[i] = 0;
    if (i == 0) *flagcnt = 0;
}

// ------------------------------ MFMA GEMM + fused epilogue -----------------
// 128x128 output tile (m x n), BK=64, 256 threads = 4 waves (2x2 of 64x64).
// A <- refT rows (m); B <- sketchT rows gathered via aidx (n). Both LDS tiles
// [row][k] with XOR k-slot swizzle: physical slot = logical ^ (row&7).
// Write side: LDS dest linear (global_load_lds), source k pre-swizzled.
// D[row=m_local][col=n_local]; C/D map: col=lane&15, row=(lane>>4)*4+reg.
#define BK 64

__global__ __launch_bounds__(256) void gemm_kernel(
    const short* __restrict__ sketchT, const short* __restrict__ refT,
    const int* __restrict__ aidx,
    const float* __restrict__ isn, const float* __restrict__ ir,
    float* __restrict__ diag, float* __restrict__ rowsum,
    int* __restrict__ rowcnt)
{
    const int mBase = blockIdx.x * 128;
    const int nBase = blockIdx.y * 128;
    const int b = blockIdx.z;
    const int tid = threadIdx.x;
    const int lane = tid & 63, wv = tid >> 6;
    const int wm = (wv >> 1) * 64, wn = (wv & 1) * 64;
    const int l15 = lane & 15, l4 = lane >> 4;
    const int l7 = lane & 7, l8 = lane >> 3;      // k-slot / row-in-chunk
    const int ksw = ((l7 ^ l8) << 3);             // swizzled k (shorts)

    __shared__ __align__(16) short Rs[128 * BK];   // refT tile    [m][k]
    __shared__ __align__(16) short As[128 * BK];   // anchor tile  [n][k]

    // per-thread source pointers for the 4 staging chunks each tile
    const short* asrc[4];
    const short* bsrc[4];
#pragma unroll
    for (int c = 0; c < 4; ++c) {
        const int row = (wv * 4 + c) * 8 + l8;    // 0..127
        asrc[c] = refT + ((size_t)b * M_ + mBase + row) * C_ + ksw;
        const int an = aidx[b * N_ + nBase + row];
        bsrc[c] = sketchT + ((size_t)b * M_ + an) * C_ + ksw;
    }

    f32x4 acc[4][4] = {};   // [m-frag][n-frag]

    for (int k0 = 0; k0 < C_; k0 += BK) {
#pragma unroll
        for (int c = 0; c < 4; ++c) {
            const int cb = wv * 4 + c;            // chunk 0..15 (1KB each)
            gload_lds16(asrc[c] + k0, (char*)Rs + cb * 1024);
            gload_lds16(bsrc[c] + k0, (char*)As + cb * 1024);
        }
        __syncthreads();   // drains vmcnt before barrier

#pragma unroll
        for (int ks = 0; ks < 2; ++ks) {
            bf16x8 pm[4], pn[4];
#pragma unroll
            for (int f = 0; f < 4; ++f) {
                const int rowA = wm + f * 16 + l15;
                const int rowB = wn + f * 16 + l15;
                const int kphys = ((ks * 4 + l4) ^ (l15 & 7)) << 3;  // shorts
                pm[f] = *reinterpret_cast<const bf16x8*>(&Rs[rowA * BK + kphys]);
                pn[f] = *reinterpret_cast<const bf16x8*>(&As[rowB * BK + kphys]);
            }
#pragma unroll
            for (int fi = 0; fi < 4; ++fi)
#pragma unroll
                for (int fj = 0; fj < 4; ++fj)
                    acc[fi][fj] = __builtin_amdgcn_mfma_f32_16x16x32_bf16(
                        pm[fi], pn[fj], acc[fi][fj], 0, 0, 0);
        }
        __syncthreads();
    }

    // epilogue: sim = dot * isn[aidx[n]] * ir[m]; diag store + relu mining
    float irv[4][4];
#pragma unroll
    for (int fi = 0; fi < 4; ++fi)
#pragma unroll
        for (int r = 0; r < 4; ++r)
            irv[fi][r] = ir[b * M_ + mBase + wm + fi * 16 + l4 * 4 + r];

#pragma unroll
    for (int fj = 0; fj < 4; ++fj) {
        const int gn = nBase + wn + fj * 16 + l15;
        const float ian = isn[b * M_ + aidx[b * N_ + gn]];
        float s = 0.f; int cnt = 0;
#pragma unroll
        for (int fi = 0; fi < 4; ++fi) {
#pragma unroll
            for (int r = 0; r < 4; ++r) {
                const int gm = mBase + wm + fi * 16 + l4 * 4 + r;
                const float sim = acc[fi][fj][r] * irv[fi][r] * ian;
                if (gm == gn) {
                    diag[b * N_ + gn] = 1.0f - sim;       // unique producer
                } else if (sim > THRESH_) {
                    s += sim - THRESH_; ++cnt;            // ~never fires
                }
            }
        }
        if (cnt) {
            atomicAdd(&rowsum[b * N_ + gn], s);
            atomicAdd(&rowcnt[b * N_ + gn], cnt);
        }
    }
}

// ------------------------- flag rows needing exact top-4 -------------------
__global__ __launch_bounds__(256) void flag_kernel(
    const int* __restrict__ rowcnt, int* __restrict__ flagcnt,
    int* __restrict__ flaglist)
{
    int i = blockIdx.x * 256 + threadIdx.x;   // b*N + n
    if (rowcnt[i] > 4) {
        int p = atomicAdd(flagcnt, 1);
        flaglist[p] = i;
    }
}

// -------- exact top-4 recompute for flagged rows (empty for this input) ----
__global__ __launch_bounds__(256) void fallback_kernel(
    const short* __restrict__ sketchT, const short* __restrict__ refT,
    const int* __restrict__ aidx,
    const float* __restrict__ isn, const float* __restrict__ ir,
    const int* __restrict__ flagcnt, const int* __restrict__ flaglist,
    float* __restrict__ rowsum)
{
    const int nflag = *flagcnt;
    __shared__ float av[C_];
    __shared__ float tops[256][4];
    for (int fi = blockIdx.x; fi < nflag; fi += gridDim.x) {
        const int row = flaglist[fi];
        const int b = row >> 12, n = row & (N_ - 1);
        const int an = aidx[row];
        __syncthreads();
        av[threadIdx.x] = bf2f(sketchT[((size_t)b * M_ + an) * C_ + threadIdx.x]);
        __syncthreads();
        const float ian = isn[b * M_ + an];
        float t0 = 0, t1 = 0, t2 = 0, t3 = 0;   // descending top-4 relu vals
        for (int m = threadIdx.x; m < M_; m += 256) {
            if (m == n) continue;
            const short* rp = refT + ((size_t)b * M_ + m) * C_;
            float dot = 0.f;
#pragma unroll 8
            for (int c = 0; c < C_; ++c) dot += av[c] * bf2f(rp[c]);
            float rl = dot * ian * ir[b * M_ + m] - THRESH_;
            if (rl > t3) {
                t3 = rl;
                if (t3 > t2) { float t = t2; t2 = t3; t3 = t; }
                if (t2 > t1) { float t = t1; t1 = t2; t2 = t; }
                if (t1 > t0) { float t = t0; t0 = t1; t1 = t; }
            }
        }
        tops[threadIdx.x][0] = t0; tops[threadIdx.x][1] = t1;
        tops[threadIdx.x][2] = t2; tops[threadIdx.x][3] = t3;
        __syncthreads();
        if (threadIdx.x == 0) {
            float s0 = 0, s1 = 0, s2 = 0, s3 = 0;
            for (int t = 0; t < 1024; ++t) {
                float v = tops[t >> 2][t & 3];
                if (v > s3) {
                    s3 = v;
                    if (s3 > s2) { float tt = s2; s2 = s3; s3 = tt; }
                    if (s2 > s1) { float tt = s1; s1 = s2; s2 = tt; }
                    if (s1 > s0) { float tt = s0; s0 = s1; s1 = tt; }
                }
            }
            rowsum[row] = s0 + s1 + s2 + s3;   // exact top-4 sum overrides
        }
        __syncthreads();
    }
}

// ------------------------------ final reduce -------------------------------
__global__ __launch_bounds__(256) void final_kernel(
    const float* __restrict__ rowsum, const float* __restrict__ diag,
    float* __restrict__ out)
{
    float sn = 0.f, sp = 0.f;
    for (int i = threadIdx.x; i < B_ * N_; i += 256) {
        sn += rowsum[i];
        sp += diag[i];
    }
    __shared__ float red[256];
    red[threadIdx.x] = sp * (1.0f / (B_ * N_)) + sn * (1.0f / (B_ * N_ * 4));
    __syncthreads();
    for (int s = 128; s > 0; s >>= 1) {
        if (threadIdx.x < s) red[threadIdx.x] += red[threadIdx.x + s];
        __syncthreads();
    }
    if (threadIdx.x == 0) out[0] = red[0];
}

// ---------------------------------------------------------------------------
extern "C" void kernel_launch(void* const* d_in, const int* in_sizes, int n_in,
                              void* d_out, int out_size, void* d_ws, size_t ws_size,
                              hipStream_t stream)
{
    const float* sketch = (const float*)d_in[0];
    const float* ref    = (const float*)d_in[1];
    const int*   ay     = (const int*)d_in[2];
    const int*   ax     = (const int*)d_in[3];
    float* out = (float*)d_out;

    char* ws = (char*)d_ws;
    short* sketchT  = (short*)(ws + OFF_SKT);
    short* refT     = (short*)(ws + OFF_REFT);
    float* isn      = (float*)(ws + OFF_ISN);
    float* ir       = (float*)(ws + OFF_IR);
    float* ssum     = (float*)(ws + OFF_SSUM);
    float* diag     = (float*)(ws + OFF_DIAG);
    float* rowsum   = (float*)(ws + OFF_ROWSUM);
    int*   rowcnt   = (int*)(ws + OFF_ROWCNT);
    int*   flagcnt  = (int*)(ws + OFF_FLAGC);
    int*   flaglist = (int*)(ws + OFF_FLAGL);
    int*   aidx     = (int*)(ws + OFF_AIDX);

    convert_kernel<<<dim3(16 * B_, 4, 2), 256, 0, stream>>>(
        sketch, ref, sketchT, refT, ssum);
    fin_kernel<<<(B_ * M_) / 256, 256, 0, stream>>>(ssum, isn, ir);
    // ssum dead from here; its region is recycled (diag..aidx)
    prep2_kernel<<<(B_ * N_) / 256, 256, 0, stream>>>(
        ay, ax, aidx, rowsum, rowcnt, flagcnt);

    gemm_kernel<<<dim3(M_ / 128, N_ / 128, B_), 256, 0, stream>>>(
        sketchT, refT, aidx, isn, ir, diag, rowsum, rowcnt);

    flag_kernel<<<(B_ * N_) / 256, 256, 0, stream>>>(rowcnt, flagcnt, flaglist);
    fallback_kernel<<<64, 256, 0, stream>>>(sketchT, refT, aidx, isn, ir,
                                            flagcnt, flaglist, rowsum);
    final_kernel<<<1, 256, 0, stream>>>(rowsum, diag, out);
}